// Round 5
// baseline (625.110 us; speedup 1.0000x reference)
//
#include <hip/hip_runtime.h>
#include <hip/hip_bf16.h>
#include <cmath>

#define NT    4096            // B*T tokens
#define CDIM  768
#define HDIM  3072
#define NEXP  8
#define SLOTS (NT * 2)        // top-2 -> 8192 (token,expert) pairs, exact
#define MT64  20              // max 64-row M-tiles per expert (1280 tokens)

typedef __bf16 bf16_t;
typedef __bf16 bf16x8 __attribute__((ext_vector_type(8)));
typedef float  f32x4  __attribute__((ext_vector_type(4)));

// async global->LDS, 16B per lane; LDS dest = wave-uniform base + lane*16
__device__ __forceinline__ void glds16(const void* g, void* l) {
    __builtin_amdgcn_global_load_lds(
        (const __attribute__((address_space(1))) void*)g,
        (__attribute__((address_space(3))) void*)l, 16, 0, 0);
}

// wait until <= n vector-memory ops outstanding (expcnt/lgkmcnt unconstrained)
#define WAITVM(n) __builtin_amdgcn_s_waitcnt(((n)&15) | (((n)>>4)<<14) | 0x70 | 0xF00)

// ---------- W fp32 (E,R,CC) -> bf16 transposed (E,CC,R), 64x64 tiles ----------
template<int R, int CC>
__global__ __launch_bounds__(256)
void transpose_convert_kernel(const float* __restrict__ in, bf16_t* __restrict__ out) {
    __shared__ float tile[64][68];
    int e = blockIdx.z;
    int c0 = blockIdx.x * 64, r0 = blockIdx.y * 64;
    const float* src = in + (size_t)e * R * CC;
    bf16_t* dst = out + (size_t)e * R * CC;
    int t = threadIdx.x;
    int c4 = (t & 15) * 4, rr = t >> 4;
    #pragma unroll
    for (int i = 0; i < 4; i++) {
        int r = rr + i * 16;
        float4 v = *reinterpret_cast<const float4*>(&src[(size_t)(r0 + r) * CC + c0 + c4]);
        tile[r][c4 + 0] = v.x; tile[r][c4 + 1] = v.y;
        tile[r][c4 + 2] = v.z; tile[r][c4 + 3] = v.w;
    }
    __syncthreads();
    #pragma unroll
    for (int i = 0; i < 4; i++) {
        int cc = rr + i * 16;
        int r4 = (t & 15) * 4;
        union { bf16_t h[4]; uint2 u; } un;
        un.h[0] = (bf16_t)tile[r4 + 0][cc]; un.h[1] = (bf16_t)tile[r4 + 1][cc];
        un.h[2] = (bf16_t)tile[r4 + 2][cc]; un.h[3] = (bf16_t)tile[r4 + 3][cc];
        *reinterpret_cast<uint2*>(&dst[(size_t)(c0 + cc) * R + r0 + r4]) = un.u;
    }
}

// ---------- router (fused x->bf16 convert): fp32 logits, softmax, top-2 ----------
__global__ __launch_bounds__(256)
void router_kernel(const float* __restrict__ x, const float* __restrict__ wg,
                   bf16_t* __restrict__ xb,
                   int* __restrict__ eidx, float* __restrict__ egate,
                   int* __restrict__ counts) {
    int lane = threadIdx.x & 63, wid = threadIdx.x >> 6;
    int t = blockIdx.x * 4 + wid;              // one wave per token
    const float* xr = x + (size_t)t * CDIM;
    float acc[NEXP];
    #pragma unroll
    for (int e = 0; e < NEXP; e++) acc[e] = 0.f;
    #pragma unroll
    for (int i = 0; i < CDIM / 256; i++) {     // 3 float4 per lane
        int c = (i * 64 + lane) * 4;
        float4 v = *reinterpret_cast<const float4*>(xr + c);
        union { bf16_t h[4]; uint2 u; } un;
        un.h[0] = (bf16_t)v.x; un.h[1] = (bf16_t)v.y;
        un.h[2] = (bf16_t)v.z; un.h[3] = (bf16_t)v.w;
        *reinterpret_cast<uint2*>(xb + (size_t)t * CDIM + c) = un.u;
        float vv[4] = {v.x, v.y, v.z, v.w};
        #pragma unroll
        for (int j = 0; j < 4; j++)
            #pragma unroll
            for (int e = 0; e < NEXP; e++)
                acc[e] += vv[j] * wg[(c + j) * NEXP + e];
    }
    #pragma unroll
    for (int e = 0; e < NEXP; e++) {
        #pragma unroll
        for (int off = 32; off > 0; off >>= 1)
            acc[e] += __shfl_xor(acc[e], off, 64);
    }
    if (lane == 0) {
        float mx = acc[0];
        #pragma unroll
        for (int e = 1; e < NEXP; e++) mx = fmaxf(mx, acc[e]);
        float p[NEXP], s = 0.f;
        #pragma unroll
        for (int e = 0; e < NEXP; e++) { p[e] = expf(acc[e] - mx); s += p[e]; }
        float inv = 1.f / s;
        int i0 = 0;
        #pragma unroll
        for (int e = 1; e < NEXP; e++) if (p[e] > p[i0]) i0 = e;   // ties -> lower idx, matches lax.top_k
        int i1 = (i0 == 0) ? 1 : 0;
        #pragma unroll
        for (int e = 0; e < NEXP; e++) if (e != i0 && p[e] > p[i1]) i1 = e;
        eidx[t * 2]      = i0;  eidx[t * 2 + 1] = i1;
        egate[t * 2]     = p[i0] * inv;
        egate[t * 2 + 1] = p[i1] * inv;
        atomicAdd(&counts[i0], 1);
        atomicAdd(&counts[i1], 1);
    }
}

// ---------- plan: per-expert offsets (tiny) ----------
__global__ void plan_kernel(const int* __restrict__ counts, int* __restrict__ curs,
                            int* __restrict__ eoff, int* __restrict__ ecnt) {
    if (threadIdx.x != 0) return;
    int off = 0;
    for (int e = 0; e < NEXP; e++) {
        int ne = counts[e];
        eoff[e] = off; ecnt[e] = ne; curs[e] = off;
        off += ne;
    }
}

// ---------- scatter tokens into per-expert contiguous slots (+ inverse map) ----------
__global__ void scatter_kernel(const int* __restrict__ eidx, const float* __restrict__ egate,
                               int* __restrict__ curs, int* __restrict__ tmap,
                               float* __restrict__ gmap, int* __restrict__ smap) {
    int t = blockIdx.x * blockDim.x + threadIdx.x;
    if (t >= NT) return;
    #pragma unroll
    for (int s = 0; s < 2; s++) {
        int e = eidx[t * 2 + s];
        int p = atomicAdd(&curs[e], 1);
        tmap[p] = t;
        gmap[p] = egate[t * 2 + s];
        smap[t * 2 + s] = p;
    }
}

// ---------- barrier-free wave-private grouped GEMM ----------
// 1 wave/block, 64x128 tile, BK=32, 4-stage LDS ring, prefetch distance 3,
// explicit s_waitcnt vmcnt(N) (never 0 in steady state), NO __syncthreads.
// FIRST: h[pos][n] = relu(bf16(X[tmap[pos]]) @ W1t[e] + b1[e])   (K=768,  N=3072)
// !FIRST: yws[pos][n] = gmap[pos]*(h[pos] @ W2t[e] + b2[e])      (K=3072, N=768)
template<int KDIM, int NDIM, bool FIRST>
__global__ __launch_bounds__(64, 1)
void moe_gemm_kernel(const bf16_t* __restrict__ Asrc, const bf16_t* __restrict__ Wt,
                     const float* __restrict__ bias,
                     const int* __restrict__ eoff, const int* __restrict__ ecnt,
                     const int* __restrict__ tmap, const float* __restrict__ gmap,
                     bf16_t* __restrict__ hout, float* __restrict__ yout) {
    constexpr int NT128 = NDIM / 128;
    constexpr int NS = KDIM / 32;              // 24 / 96 K-steps
    int h = blockIdx.x;
    int e = h & 7;                             // expert <-> XCD partition
    int local = h >> 3;
    int mt = local / NT128;
    int nt = local - mt * NT128;
    int cnt = ecnt[e];
    if (mt * 64 >= cnt) return;
    int m0 = eoff[e] + mt * 64;
    int rend = eoff[e] + cnt;
    int n0 = nt * 128;

    // wave-private ring: 4 stages x (A 64x32 + B 128x32) bf16 = 48KB -> 3 blocks/CU
    __shared__ __attribute__((aligned(16))) bf16_t As[4 * 64 * 32];
    __shared__ __attribute__((aligned(16))) bf16_t Bs[4 * 128 * 32];

    int lane = threadIdx.x;
    int srow = lane >> 2;                      // 16 rows per glds16
    int sch  = (lane & 3) * 8;                 // 16B chunk within 64B row

    const bf16_t* aP[4];
    #pragma unroll
    for (int i = 0; i < 4; i++) {
        int pos = m0 + i * 16 + srow;
        if (pos > rend - 1) pos = rend - 1;    // clamp: duplicate row, masked in epilogue
        int arow = FIRST ? tmap[pos] : pos;
        aP[i] = Asrc + (size_t)arow * KDIM + sch;
    }
    const bf16_t* bP[8];
    #pragma unroll
    for (int i = 0; i < 8; i++)
        bP[i] = Wt + ((size_t)e * NDIM + n0 + i * 16 + srow) * KDIM + sch;

    int q = lane >> 4, mr = lane & 15;

    f32x4 acc[4][8];
    #pragma unroll
    for (int i = 0; i < 4; i++)
        #pragma unroll
        for (int j = 0; j < 8; j++)
            acc[i][j] = (f32x4){0.f, 0.f, 0.f, 0.f};

    auto stage = [&](int buf, int kidx) {      // 12 glds16 (12KB) per stage
        int k = kidx * 32;
        bf16_t* ab = As + buf * 2048;
        bf16_t* bb = Bs + buf * 4096;
        #pragma unroll
        for (int i = 0; i < 4; i++) glds16(aP[i] + k, ab + i * 512);
        #pragma unroll
        for (int i = 0; i < 8; i++) glds16(bP[i] + k, bb + i * 512);
    };
    auto compute = [&](int buf) {              // 12 ds_read_b128 + 32 MFMA
        const bf16_t* ab = As + buf * 2048;
        const bf16_t* bb = Bs + buf * 4096;
        bf16x8 af[4], bfr[8];
        #pragma unroll
        for (int ti = 0; ti < 4; ti++)
            af[ti] = *reinterpret_cast<const bf16x8*>(ab + (ti * 16 + mr) * 32 + q * 8);
        #pragma unroll
        for (int tj = 0; tj < 8; tj++)
            bfr[tj] = *reinterpret_cast<const bf16x8*>(bb + (tj * 16 + mr) * 32 + q * 8);
        #pragma unroll
        for (int ti = 0; ti < 4; ti++)
            #pragma unroll
            for (int tj = 0; tj < 8; tj++)
                acc[ti][tj] = __builtin_amdgcn_mfma_f32_16x16x32_bf16(af[ti], bfr[tj], acc[ti][tj], 0, 0, 0);
    };

    stage(0, 0); stage(1, 1); stage(2, 2);     // 36 loads in flight
    for (int s = 0; s < NS - 3; s++) {
        stage((s + 3) & 3, s + 3);             // 48 in flight
        WAITVM(36);                            // oldest stage (s) complete
        compute(s & 3);
    }
    WAITVM(24); compute((NS - 3) & 3);
    WAITVM(12); compute((NS - 2) & 3);
    WAITVM(0);  compute((NS - 1) & 3);

    // epilogue: D[row=q*4+r][col=mr] per 16x16 tile
    const float* be = bias + (size_t)e * NDIM + n0;
    #pragma unroll
    for (int ti = 0; ti < 4; ti++) {
        #pragma unroll
        for (int r = 0; r < 4; r++) {
            int pos = m0 + ti * 16 + q * 4 + r;
            if (pos < rend) {
                if (FIRST) {
                    bf16_t* hrow = hout + (size_t)pos * NDIM + n0;
                    #pragma unroll
                    for (int tj = 0; tj < 8; tj++) {
                        float v = acc[ti][tj][r] + be[tj * 16 + mr];
                        hrow[tj * 16 + mr] = (bf16_t)fmaxf(v, 0.f);
                    }
                } else {
                    float g = gmap[pos];
                    float* yrow = yout + (size_t)pos * NDIM + n0;
                    #pragma unroll
                    for (int tj = 0; tj < 8; tj++) {
                        float v = acc[ti][tj][r] + be[tj * 16 + mr];
                        yrow[tj * 16 + mr] = g * v;
                    }
                }
            }
        }
    }
}

// ---------- combine: out[t] = yws[slot0(t)] + yws[slot1(t)] ----------
__global__ __launch_bounds__(256)
void combine_kernel(const float* __restrict__ yws, const int* __restrict__ smap,
                    float* __restrict__ out) {
    int idx = blockIdx.x * 256 + threadIdx.x;  // one float4 per thread
    int t = idx / (CDIM / 4);
    int c = (idx - t * (CDIM / 4)) * 4;
    int s0 = smap[t * 2], s1 = smap[t * 2 + 1];
    float4 a = *reinterpret_cast<const float4*>(yws + (size_t)s0 * CDIM + c);
    float4 b = *reinterpret_cast<const float4*>(yws + (size_t)s1 * CDIM + c);
    float4 o = {a.x + b.x, a.y + b.y, a.z + b.z, a.w + b.w};
    *reinterpret_cast<float4*>(out + (size_t)t * CDIM + c) = o;
}

extern "C" void kernel_launch(void* const* d_in, const int* in_sizes, int n_in,
                              void* d_out, int out_size, void* d_ws, size_t ws_size,
                              hipStream_t stream) {
    const float* x  = (const float*)d_in[0];
    const float* wg = (const float*)d_in[1];
    const float* w1 = (const float*)d_in[2];
    const float* b1 = (const float*)d_in[3];
    const float* w2 = (const float*)d_in[4];
    const float* b2 = (const float*)d_in[5];
    float* out = (float*)d_out;

    char* w = (char*)d_ws;
    size_t off = 0;
    bf16_t* xb  = (bf16_t*)(w + off); off += (size_t)NT * CDIM * 2;             // 6.3 MB
    bf16_t* w1t = (bf16_t*)(w + off); off += (size_t)NEXP * CDIM * HDIM * 2;    // 37.7 MB
    bf16_t* w2t = (bf16_t*)(w + off); off += (size_t)NEXP * CDIM * HDIM * 2;    // 37.7 MB
    bf16_t* hws = (bf16_t*)(w + off); off += (size_t)SLOTS * HDIM * 2;          // 50.3 MB
    float* yws  = (float*)w1t;      // 25.2 MB, aliases w1t (dead during GEMM2)
    int* counts   = (int*)(w + off);
    int* curs     = counts + NEXP;
    int* eoff     = counts + 2 * NEXP;
    int* ecnt     = counts + 3 * NEXP;
    int* eidx     = counts + 4 * NEXP;
    int* tmap     = eidx + SLOTS;
    int* smap     = tmap + SLOTS;
    float* egate  = (float*)(smap + SLOTS);
    float* gmap   = egate + SLOTS;

    hipMemsetAsync(counts, 0, NEXP * sizeof(int), stream);

    transpose_convert_kernel<CDIM, HDIM>
        <<<dim3(HDIM / 64, CDIM / 64, NEXP), 256, 0, stream>>>(w1, w1t);
    transpose_convert_kernel<HDIM, CDIM>
        <<<dim3(CDIM / 64, HDIM / 64, NEXP), 256, 0, stream>>>(w2, w2t);
    router_kernel<<<NT / 4, 256, 0, stream>>>(x, wg, xb, eidx, egate, counts);
    plan_kernel<<<1, 64, 0, stream>>>(counts, curs, eoff, ecnt);
    scatter_kernel<<<NT / 256, 256, 0, stream>>>(eidx, egate, curs, tmap, gmap, smap);

    // 1-D grids: expert = id&7 (XCD partition), then M64-tile x N128-tile
    moe_gemm_kernel<CDIM, HDIM, true>
        <<<8 * MT64 * (HDIM / 128), 64, 0, stream>>>(
            xb, w1t, b1, eoff, ecnt, tmap, gmap, hws, nullptr);
    moe_gemm_kernel<HDIM, CDIM, false>
        <<<8 * MT64 * (CDIM / 128), 64, 0, stream>>>(
            hws, w2t, b2, eoff, ecnt, tmap, gmap, nullptr, yws);
    combine_kernel<<<NT * (CDIM / 4) / 256, 256, 0, stream>>>(yws, smap, out);
}

// Round 6
// 440.263 us; speedup vs baseline: 1.4199x; 1.4199x over previous
//
#include <hip/hip_runtime.h>
#include <hip/hip_bf16.h>
#include <cmath>

#define NT    4096            // B*T tokens
#define CDIM  768
#define HDIM  3072
#define NEXP  8
#define CAP   1280            // fixed slot capacity per expert (>=9 sigma headroom)

typedef __bf16 bf16_t;
typedef __bf16 bf16x8 __attribute__((ext_vector_type(8)));
typedef float  f32x4  __attribute__((ext_vector_type(4)));

// async global->LDS, 16B per lane; LDS dest = wave-uniform base + lane*16
__device__ __forceinline__ void glds16(const void* g, void* l) {
    __builtin_amdgcn_global_load_lds(
        (const __attribute__((address_space(1))) void*)g,
        (__attribute__((address_space(3))) void*)l, 16, 0, 0);
}

// ---------- W fp32 (E,R,CC) -> bf16 transposed (E,CC,R), 64x64 tiles ----------
template<int R, int CC>
__global__ __launch_bounds__(256)
void transpose_convert_kernel(const float* __restrict__ in, bf16_t* __restrict__ out) {
    __shared__ float tile[64][68];
    int e = blockIdx.z;
    int c0 = blockIdx.x * 64, r0 = blockIdx.y * 64;
    const float* src = in + (size_t)e * R * CC;
    bf16_t* dst = out + (size_t)e * R * CC;
    int t = threadIdx.x;
    int c4 = (t & 15) * 4, rr = t >> 4;
    #pragma unroll
    for (int i = 0; i < 4; i++) {
        int r = rr + i * 16;
        float4 v = *reinterpret_cast<const float4*>(&src[(size_t)(r0 + r) * CC + c0 + c4]);
        tile[r][c4 + 0] = v.x; tile[r][c4 + 1] = v.y;
        tile[r][c4 + 2] = v.z; tile[r][c4 + 3] = v.w;
    }
    __syncthreads();
    #pragma unroll
    for (int i = 0; i < 4; i++) {
        int cc = rr + i * 16;
        int r4 = (t & 15) * 4;
        union { bf16_t h[4]; uint2 u; } un;
        un.h[0] = (bf16_t)tile[r4 + 0][cc]; un.h[1] = (bf16_t)tile[r4 + 1][cc];
        un.h[2] = (bf16_t)tile[r4 + 2][cc]; un.h[3] = (bf16_t)tile[r4 + 3][cc];
        *reinterpret_cast<uint2*>(&dst[(size_t)(c0 + cc) * R + r0 + r4]) = un.u;
    }
}

// ---------- router (fused x->bf16 convert + slot assignment, no plan/scatter) --
__global__ __launch_bounds__(256)
void router_kernel(const float* __restrict__ x, const float* __restrict__ wg,
                   bf16_t* __restrict__ xb,
                   int* __restrict__ counts, int* __restrict__ tmap,
                   float* __restrict__ gmap, int* __restrict__ smap) {
    int lane = threadIdx.x & 63, wid = threadIdx.x >> 6;
    int t = blockIdx.x * 4 + wid;              // one wave per token
    const float* xr = x + (size_t)t * CDIM;
    float acc[NEXP];
    #pragma unroll
    for (int e = 0; e < NEXP; e++) acc[e] = 0.f;
    #pragma unroll
    for (int i = 0; i < CDIM / 256; i++) {     // 3 float4 per lane
        int c = (i * 64 + lane) * 4;
        float4 v = *reinterpret_cast<const float4*>(xr + c);
        union { bf16_t h[4]; uint2 u; } un;
        un.h[0] = (bf16_t)v.x; un.h[1] = (bf16_t)v.y;
        un.h[2] = (bf16_t)v.z; un.h[3] = (bf16_t)v.w;
        *reinterpret_cast<uint2*>(xb + (size_t)t * CDIM + c) = un.u;
        float vv[4] = {v.x, v.y, v.z, v.w};
        #pragma unroll
        for (int j = 0; j < 4; j++)
            #pragma unroll
            for (int e = 0; e < NEXP; e++)
                acc[e] += vv[j] * wg[(c + j) * NEXP + e];
    }
    #pragma unroll
    for (int e = 0; e < NEXP; e++) {
        #pragma unroll
        for (int off = 32; off > 0; off >>= 1)
            acc[e] += __shfl_xor(acc[e], off, 64);
    }
    if (lane == 0) {
        float mx = acc[0];
        #pragma unroll
        for (int e = 1; e < NEXP; e++) mx = fmaxf(mx, acc[e]);
        float p[NEXP], s = 0.f;
        #pragma unroll
        for (int e = 0; e < NEXP; e++) { p[e] = expf(acc[e] - mx); s += p[e]; }
        float inv = 1.f / s;
        int i0 = 0;
        #pragma unroll
        for (int e = 1; e < NEXP; e++) if (p[e] > p[i0]) i0 = e;   // ties -> lower idx, matches lax.top_k
        int i1 = (i0 == 0) ? 1 : 0;
        #pragma unroll
        for (int e = 0; e < NEXP; e++) if (e != i0 && p[e] > p[i1]) i1 = e;
        int c0 = atomicAdd(&counts[i0], 1); if (c0 >= CAP) c0 = CAP - 1;
        int c1 = atomicAdd(&counts[i1], 1); if (c1 >= CAP) c1 = CAP - 1;
        int s0 = i0 * CAP + c0, s1 = i1 * CAP + c1;
        tmap[s0] = t; gmap[s0] = p[i0] * inv; smap[t * 2]     = s0;
        tmap[s1] = t; gmap[s1] = p[i1] * inv; smap[t * 2 + 1] = s1;
    }
}

// ---------- GEMM1: m97-shape 128x128, BK=32, expert<->XCD partition ----------
// h[pos][n] = relu(bf16(X[tmap[pos]]) @ W1t[e] + b1[e])   (K=768, N=3072)
__global__ __launch_bounds__(256)
void moe_gemm1_kernel(const bf16_t* __restrict__ xb, const bf16_t* __restrict__ w1t,
                      const float* __restrict__ b1, const int* __restrict__ counts,
                      const int* __restrict__ tmap, bf16_t* __restrict__ hws) {
    int h = blockIdx.x;
    int e = h & 7;                             // expert <-> XCD partition
    int local = h >> 3;
    int mt = local / (HDIM / 128);
    int nt = local - mt * (HDIM / 128);
    int cnt = counts[e]; if (cnt > CAP) cnt = CAP;
    if (mt * 128 >= cnt) return;
    int m0 = e * CAP + mt * 128;
    int rend = e * CAP + cnt;
    int n0 = nt * 128;

    __shared__ __attribute__((aligned(16))) bf16_t As[128 * 32];   // 8KB
    __shared__ __attribute__((aligned(16))) bf16_t Bs[128 * 32];   // 8KB

    int tid = threadIdx.x, lane = tid & 63, wid = tid >> 6;
    const bf16_t* aP[2];
    const bf16_t* bP[2];
    int reg[2];
    #pragma unroll
    for (int it = 0; it < 2; it++) {
        int region = wid * 2 + it;             // 8 regions x 16 rows
        int row = region * 16 + (lane >> 2);
        int kk = (lane & 3) * 8;
        int pos = m0 + row;
        if (pos > rend - 1) pos = rend - 1;    // clamp, masked in epilogue
        aP[it] = xb + (size_t)tmap[pos] * CDIM + kk;
        bP[it] = w1t + ((size_t)e * HDIM + n0 + row) * CDIM + kk;
        reg[it] = region * 512;                // 1KB wave-uniform LDS region
    }

    int wm = (wid >> 1) * 64, wn = (wid & 1) * 64;
    int q = lane >> 4, mr = lane & 15;

    f32x4 acc[4][4];
    #pragma unroll
    for (int i = 0; i < 4; i++)
        #pragma unroll
        for (int j = 0; j < 4; j++)
            acc[i][j] = (f32x4){0.f, 0.f, 0.f, 0.f};

    for (int k0 = 0; k0 < CDIM; k0 += 32) {
        #pragma unroll
        for (int it = 0; it < 2; it++) {
            glds16(aP[it] + k0, As + reg[it]);
            glds16(bP[it] + k0, Bs + reg[it]);
        }
        __syncthreads();
        bf16x8 af[4], bfr[4];
        #pragma unroll
        for (int ti = 0; ti < 4; ti++)
            af[ti] = *reinterpret_cast<const bf16x8*>(&As[(wm + ti * 16 + mr) * 32 + q * 8]);
        #pragma unroll
        for (int tj = 0; tj < 4; tj++)
            bfr[tj] = *reinterpret_cast<const bf16x8*>(&Bs[(wn + tj * 16 + mr) * 32 + q * 8]);
        #pragma unroll
        for (int ti = 0; ti < 4; ti++)
            #pragma unroll
            for (int tj = 0; tj < 4; tj++)
                acc[ti][tj] = __builtin_amdgcn_mfma_f32_16x16x32_bf16(af[ti], bfr[tj], acc[ti][tj], 0, 0, 0);
        __syncthreads();
    }

    const float* be = b1 + (size_t)e * HDIM + n0;
    #pragma unroll
    for (int ti = 0; ti < 4; ti++) {
        #pragma unroll
        for (int r = 0; r < 4; r++) {
            int pos = m0 + wm + ti * 16 + q * 4 + r;
            if (pos < rend) {
                bf16_t* hrow = hws + (size_t)pos * HDIM + n0;
                #pragma unroll
                for (int tj = 0; tj < 4; tj++) {
                    float v = acc[ti][tj][r] + be[wn + tj * 16 + mr];
                    hrow[wn + tj * 16 + mr] = (bf16_t)fmaxf(v, 0.f);
                }
            }
        }
    }
}

// ---------- GEMM2: 64x128 tile, BK=32, no split-K, no atomics ----------
// yws[pos][c] = gmap[pos] * (h[pos] @ W2t[e] + b2[e])   (K=3072, N=768)
__global__ __launch_bounds__(256)
void moe_gemm2_kernel(const bf16_t* __restrict__ hws, const bf16_t* __restrict__ w2t,
                      const float* __restrict__ b2, const int* __restrict__ counts,
                      const float* __restrict__ gmap, float* __restrict__ yws) {
    int h = blockIdx.x;
    int e = h & 7;
    int local = h >> 3;
    int mt = local / (CDIM / 128);
    int nt = local - mt * (CDIM / 128);
    int cnt = counts[e]; if (cnt > CAP) cnt = CAP;
    if (mt * 64 >= cnt) return;
    int m0 = e * CAP + mt * 64;
    int rend = e * CAP + cnt;
    int n0 = nt * 128;

    __shared__ __attribute__((aligned(16))) bf16_t As[64 * 32];    // 4KB
    __shared__ __attribute__((aligned(16))) bf16_t Bs[128 * 32];   // 8KB

    int tid = threadIdx.x, lane = tid & 63, wid = tid >> 6;
    // A staging: 4 regions x 16 rows, 1 glds16/thread
    int arowL = wid * 16 + (lane >> 2);
    int kk = (lane & 3) * 8;
    int aposc = m0 + arowL; if (aposc > rend - 1) aposc = rend - 1;
    const bf16_t* aP = hws + (size_t)aposc * HDIM + kk;
    int aReg = wid * 512;
    // B staging: 8 regions x 16 rows, 2 glds16/thread
    const bf16_t* bP[2];
    int bReg[2];
    #pragma unroll
    for (int it = 0; it < 2; it++) {
        int region = wid * 2 + it;
        int row = region * 16 + (lane >> 2);
        bP[it] = w2t + ((size_t)e * CDIM + n0 + row) * HDIM + kk;
        bReg[it] = region * 512;
    }

    int wm = (wid & 1) * 32, wn = (wid >> 1) * 64;
    int q = lane >> 4, mr = lane & 15;

    f32x4 acc[2][4];
    #pragma unroll
    for (int i = 0; i < 2; i++)
        #pragma unroll
        for (int j = 0; j < 4; j++)
            acc[i][j] = (f32x4){0.f, 0.f, 0.f, 0.f};

    for (int k0 = 0; k0 < HDIM; k0 += 32) {
        glds16(aP + k0, As + aReg);
        #pragma unroll
        for (int it = 0; it < 2; it++)
            glds16(bP[it] + k0, Bs + bReg[it]);
        __syncthreads();
        bf16x8 af[2], bfr[4];
        #pragma unroll
        for (int ti = 0; ti < 2; ti++)
            af[ti] = *reinterpret_cast<const bf16x8*>(&As[(wm + ti * 16 + mr) * 32 + q * 8]);
        #pragma unroll
        for (int tj = 0; tj < 4; tj++)
            bfr[tj] = *reinterpret_cast<const bf16x8*>(&Bs[(wn + tj * 16 + mr) * 32 + q * 8]);
        #pragma unroll
        for (int ti = 0; ti < 2; ti++)
            #pragma unroll
            for (int tj = 0; tj < 4; tj++)
                acc[ti][tj] = __builtin_amdgcn_mfma_f32_16x16x32_bf16(af[ti], bfr[tj], acc[ti][tj], 0, 0, 0);
        __syncthreads();
    }

    const float* be = b2 + (size_t)e * CDIM + n0;
    #pragma unroll
    for (int ti = 0; ti < 2; ti++) {
        #pragma unroll
        for (int r = 0; r < 4; r++) {
            int pos = m0 + wm + ti * 16 + q * 4 + r;
            if (pos < rend) {
                float g = gmap[pos];
                float* yrow = yws + (size_t)pos * CDIM + n0;
                #pragma unroll
                for (int tj = 0; tj < 4; tj++) {
                    float v = acc[ti][tj][r] + be[wn + tj * 16 + mr];
                    yrow[wn + tj * 16 + mr] = g * v;
                }
            }
        }
    }
}

// ---------- combine: out[t] = yws[slot0(t)] + yws[slot1(t)] ----------
__global__ __launch_bounds__(256)
void combine_kernel(const float* __restrict__ yws, const int* __restrict__ smap,
                    float* __restrict__ out) {
    int idx = blockIdx.x * 256 + threadIdx.x;  // one float4 per thread
    int t = idx / (CDIM / 4);
    int c = (idx - t * (CDIM / 4)) * 4;
    int s0 = smap[t * 2], s1 = smap[t * 2 + 1];
    float4 a = *reinterpret_cast<const float4*>(yws + (size_t)s0 * CDIM + c);
    float4 b = *reinterpret_cast<const float4*>(yws + (size_t)s1 * CDIM + c);
    float4 o = {a.x + b.x, a.y + b.y, a.z + b.z, a.w + b.w};
    *reinterpret_cast<float4*>(out + (size_t)t * CDIM + c) = o;
}

extern "C" void kernel_launch(void* const* d_in, const int* in_sizes, int n_in,
                              void* d_out, int out_size, void* d_ws, size_t ws_size,
                              hipStream_t stream) {
    const float* x  = (const float*)d_in[0];
    const float* wg = (const float*)d_in[1];
    const float* w1 = (const float*)d_in[2];
    const float* b1 = (const float*)d_in[3];
    const float* w2 = (const float*)d_in[4];
    const float* b2 = (const float*)d_in[5];
    float* out = (float*)d_out;

    char* w = (char*)d_ws;
    size_t off = 0;
    bf16_t* xb  = (bf16_t*)(w + off); off += (size_t)NT * CDIM * 2;             // 6.3 MB
    bf16_t* w1t = (bf16_t*)(w + off); off += (size_t)NEXP * CDIM * HDIM * 2;    // 37.7 MB
    bf16_t* w2t = (bf16_t*)(w + off); off += (size_t)NEXP * CDIM * HDIM * 2;    // 37.7 MB
    bf16_t* hws = (bf16_t*)(w + off); off += (size_t)NEXP * CAP * HDIM * 2;     // 62.9 MB
    float* yws  = (float*)w1t;      // 31.5 MB, aliases w1t (dead after GEMM1)
    int* counts = (int*)(w + off);  off += 64;
    int* tmap   = (int*)(w + off);  off += (size_t)NEXP * CAP * 4;
    int* smap   = (int*)(w + off);  off += (size_t)NT * 2 * 4;
    float* gmap = (float*)(w + off);

    hipMemsetAsync(counts, 0, NEXP * sizeof(int), stream);

    transpose_convert_kernel<CDIM, HDIM>
        <<<dim3(HDIM / 64, CDIM / 64, NEXP), 256, 0, stream>>>(w1, w1t);
    transpose_convert_kernel<HDIM, CDIM>
        <<<dim3(CDIM / 64, HDIM / 64, NEXP), 256, 0, stream>>>(w2, w2t);
    router_kernel<<<NT / 4, 256, 0, stream>>>(x, wg, xb, counts, tmap, gmap, smap);

    moe_gemm1_kernel<<<8 * (CAP / 128) * (HDIM / 128), 256, 0, stream>>>(
        xb, w1t, b1, counts, tmap, hws);
    moe_gemm2_kernel<<<8 * (CAP / 64) * (CDIM / 128), 256, 0, stream>>>(
        hws, w2t, b2, counts, gmap, yws);
    combine_kernel<<<NT * (CDIM / 4) / 256, 256, 0, stream>>>(yws, smap, out);
}

// Round 7
// 371.861 us; speedup vs baseline: 1.6810x; 1.1839x over previous
//
#include <hip/hip_runtime.h>
#include <hip/hip_bf16.h>
#include <cmath>

#define NT    4096            // B*T tokens
#define CDIM  768
#define HDIM  3072
#define NEXP  8
#define CAP   1280            // fixed slot capacity per expert (>=9 sigma headroom)

typedef __bf16 bf16_t;
typedef __bf16 bf16x8 __attribute__((ext_vector_type(8)));
typedef float  f32x4  __attribute__((ext_vector_type(4)));

// async global->LDS, 16B per lane; LDS dest = wave-uniform base + lane*16
__device__ __forceinline__ void glds16(const void* g, void* l) {
    __builtin_amdgcn_global_load_lds(
        (const __attribute__((address_space(1))) void*)g,
        (__attribute__((address_space(3))) void*)l, 16, 0, 0);
}

// ---------- W fp32 (E,R,CC) -> bf16 transposed (E,CC,R), 64x64 tiles ----------
template<int R, int CC>
__global__ __launch_bounds__(256)
void transpose_convert_kernel(const float* __restrict__ in, bf16_t* __restrict__ out) {
    __shared__ float tile[64][68];
    int e = blockIdx.z;
    int c0 = blockIdx.x * 64, r0 = blockIdx.y * 64;
    const float* src = in + (size_t)e * R * CC;
    bf16_t* dst = out + (size_t)e * R * CC;
    int t = threadIdx.x;
    int c4 = (t & 15) * 4, rr = t >> 4;
    #pragma unroll
    for (int i = 0; i < 4; i++) {
        int r = rr + i * 16;
        float4 v = *reinterpret_cast<const float4*>(&src[(size_t)(r0 + r) * CC + c0 + c4]);
        tile[r][c4 + 0] = v.x; tile[r][c4 + 1] = v.y;
        tile[r][c4 + 2] = v.z; tile[r][c4 + 3] = v.w;
    }
    __syncthreads();
    #pragma unroll
    for (int i = 0; i < 4; i++) {
        int cc = rr + i * 16;
        int r4 = (t & 15) * 4;
        union { bf16_t h[4]; uint2 u; } un;
        un.h[0] = (bf16_t)tile[r4 + 0][cc]; un.h[1] = (bf16_t)tile[r4 + 1][cc];
        un.h[2] = (bf16_t)tile[r4 + 2][cc]; un.h[3] = (bf16_t)tile[r4 + 3][cc];
        *reinterpret_cast<uint2*>(&dst[(size_t)(c0 + cc) * R + r0 + r4]) = un.u;
    }
}

// ---------- router: fused x->bf16 + top-2 + hierarchical slot assignment ------
// 512 thr = 8 waves x 4 tokens = 32 tokens/block. LDS atomics for local rank,
// ONE global atomicAdd per expert per block (kills the 8-address contention
// that made the old router 107us).
__global__ __launch_bounds__(512)
void router_kernel(const float* __restrict__ x, const float* __restrict__ wg,
                   bf16_t* __restrict__ xb,
                   int* __restrict__ counts, int* __restrict__ tmap,
                   float* __restrict__ gmap, int* __restrict__ smap) {
    __shared__ int lcnt[NEXP];
    __shared__ int gbase[NEXP];
    int tid = threadIdx.x, lane = tid & 63, wid = tid >> 6;
    if (tid < NEXP) lcnt[tid] = 0;
    __syncthreads();

    int ti0[4], ti1[4], tr0[4], tr1[4];
    float tg0[4], tg1[4];

    #pragma unroll
    for (int k = 0; k < 4; k++) {
        int t = blockIdx.x * 32 + wid * 4 + k;
        const float* xr = x + (size_t)t * CDIM;
        float acc[NEXP];
        #pragma unroll
        for (int e = 0; e < NEXP; e++) acc[e] = 0.f;
        #pragma unroll
        for (int i = 0; i < CDIM / 256; i++) {     // 3 float4 per lane
            int c = (i * 64 + lane) * 4;
            float4 v = *reinterpret_cast<const float4*>(xr + c);
            union { bf16_t h[4]; uint2 u; } un;
            un.h[0] = (bf16_t)v.x; un.h[1] = (bf16_t)v.y;
            un.h[2] = (bf16_t)v.z; un.h[3] = (bf16_t)v.w;
            *reinterpret_cast<uint2*>(xb + (size_t)t * CDIM + c) = un.u;
            float vv[4] = {v.x, v.y, v.z, v.w};
            #pragma unroll
            for (int j = 0; j < 4; j++)
                #pragma unroll
                for (int e = 0; e < NEXP; e++)
                    acc[e] += vv[j] * wg[(c + j) * NEXP + e];
        }
        #pragma unroll
        for (int e = 0; e < NEXP; e++) {
            #pragma unroll
            for (int off = 32; off > 0; off >>= 1)
                acc[e] += __shfl_xor(acc[e], off, 64);
        }
        if (lane == 0) {
            float mx = acc[0];
            #pragma unroll
            for (int e = 1; e < NEXP; e++) mx = fmaxf(mx, acc[e]);
            float p[NEXP], s = 0.f;
            #pragma unroll
            for (int e = 0; e < NEXP; e++) { p[e] = expf(acc[e] - mx); s += p[e]; }
            float inv = 1.f / s;
            int i0 = 0;
            #pragma unroll
            for (int e = 1; e < NEXP; e++) if (p[e] > p[i0]) i0 = e;  // ties -> lower idx
            int i1 = (i0 == 0) ? 1 : 0;
            #pragma unroll
            for (int e = 0; e < NEXP; e++) if (e != i0 && p[e] > p[i1]) i1 = e;
            ti0[k] = i0; ti1[k] = i1;
            tg0[k] = p[i0] * inv; tg1[k] = p[i1] * inv;
            tr0[k] = atomicAdd(&lcnt[i0], 1);      // LDS atomic: fast
            tr1[k] = atomicAdd(&lcnt[i1], 1);
        }
    }
    __syncthreads();
    if (tid < NEXP) gbase[tid] = atomicAdd(&counts[tid], lcnt[tid]);  // 8 global atomics/block
    __syncthreads();
    if (lane == 0) {
        #pragma unroll
        for (int k = 0; k < 4; k++) {
            int t = blockIdx.x * 32 + wid * 4 + k;
            int c0 = gbase[ti0[k]] + tr0[k]; if (c0 >= CAP) c0 = CAP - 1;
            int c1 = gbase[ti1[k]] + tr1[k]; if (c1 >= CAP) c1 = CAP - 1;
            int s0 = ti0[k] * CAP + c0, s1 = ti1[k] * CAP + c1;
            tmap[s0] = t; gmap[s0] = tg0[k]; smap[t * 2]     = s0;
            tmap[s1] = t; gmap[s1] = tg1[k]; smap[t * 2 + 1] = s1;
        }
    }
}

// ---------- GEMM1: m97-shape 128x128, BK=32, expert<->XCD partition ----------
// h[pos][n] = relu(bf16(X[tmap[pos]]) @ W1t[e] + b1[e])   (K=768, N=3072)
__global__ __launch_bounds__(256)
void moe_gemm1_kernel(const bf16_t* __restrict__ xb, const bf16_t* __restrict__ w1t,
                      const float* __restrict__ b1, const int* __restrict__ counts,
                      const int* __restrict__ tmap, bf16_t* __restrict__ hws) {
    int h = blockIdx.x;
    int e = h & 7;                             // expert <-> XCD partition
    int local = h >> 3;
    int mt = local / (HDIM / 128);
    int nt = local - mt * (HDIM / 128);
    int cnt = counts[e]; if (cnt > CAP) cnt = CAP;
    if (mt * 128 >= cnt) return;
    int m0 = e * CAP + mt * 128;
    int rend = e * CAP + cnt;
    int n0 = nt * 128;

    __shared__ __attribute__((aligned(16))) bf16_t As[128 * 32];   // 8KB
    __shared__ __attribute__((aligned(16))) bf16_t Bs[128 * 32];   // 8KB

    int tid = threadIdx.x, lane = tid & 63, wid = tid >> 6;
    const bf16_t* aP[2];
    const bf16_t* bP[2];
    int reg[2];
    #pragma unroll
    for (int it = 0; it < 2; it++) {
        int region = wid * 2 + it;             // 8 regions x 16 rows
        int row = region * 16 + (lane >> 2);
        int kk = (lane & 3) * 8;
        int pos = m0 + row;
        if (pos > rend - 1) pos = rend - 1;    // clamp, masked in epilogue
        aP[it] = xb + (size_t)tmap[pos] * CDIM + kk;
        bP[it] = w1t + ((size_t)e * HDIM + n0 + row) * CDIM + kk;
        reg[it] = region * 512;                // 1KB wave-uniform LDS region
    }

    int wm = (wid >> 1) * 64, wn = (wid & 1) * 64;
    int q = lane >> 4, mr = lane & 15;

    f32x4 acc[4][4];
    #pragma unroll
    for (int i = 0; i < 4; i++)
        #pragma unroll
        for (int j = 0; j < 4; j++)
            acc[i][j] = (f32x4){0.f, 0.f, 0.f, 0.f};

    for (int k0 = 0; k0 < CDIM; k0 += 32) {
        #pragma unroll
        for (int it = 0; it < 2; it++) {
            glds16(aP[it] + k0, As + reg[it]);
            glds16(bP[it] + k0, Bs + reg[it]);
        }
        __syncthreads();
        bf16x8 af[4], bfr[4];
        #pragma unroll
        for (int ti = 0; ti < 4; ti++)
            af[ti] = *reinterpret_cast<const bf16x8*>(&As[(wm + ti * 16 + mr) * 32 + q * 8]);
        #pragma unroll
        for (int tj = 0; tj < 4; tj++)
            bfr[tj] = *reinterpret_cast<const bf16x8*>(&Bs[(wn + tj * 16 + mr) * 32 + q * 8]);
        #pragma unroll
        for (int ti = 0; ti < 4; ti++)
            #pragma unroll
            for (int tj = 0; tj < 4; tj++)
                acc[ti][tj] = __builtin_amdgcn_mfma_f32_16x16x32_bf16(af[ti], bfr[tj], acc[ti][tj], 0, 0, 0);
        __syncthreads();
    }

    const float* be = b1 + (size_t)e * HDIM + n0;
    #pragma unroll
    for (int ti = 0; ti < 4; ti++) {
        #pragma unroll
        for (int r = 0; r < 4; r++) {
            int pos = m0 + wm + ti * 16 + q * 4 + r;
            if (pos < rend) {
                bf16_t* hrow = hws + (size_t)pos * HDIM + n0;
                #pragma unroll
                for (int tj = 0; tj < 4; tj++) {
                    float v = acc[ti][tj][r] + be[wn + tj * 16 + mr];
                    hrow[wn + tj * 16 + mr] = (bf16_t)fmaxf(v, 0.f);
                }
            }
        }
    }
}

// ---------- GEMM2: 64x128 tile, BK=32, no split-K, no atomics ----------
// yws[pos][c] = gmap[pos] * (h[pos] @ W2t[e] + b2[e])   (K=3072, N=768)
__global__ __launch_bounds__(256)
void moe_gemm2_kernel(const bf16_t* __restrict__ hws, const bf16_t* __restrict__ w2t,
                      const float* __restrict__ b2, const int* __restrict__ counts,
                      const float* __restrict__ gmap, float* __restrict__ yws) {
    int h = blockIdx.x;
    int e = h & 7;
    int local = h >> 3;
    int mt = local / (CDIM / 128);
    int nt = local - mt * (CDIM / 128);
    int cnt = counts[e]; if (cnt > CAP) cnt = CAP;
    if (mt * 64 >= cnt) return;
    int m0 = e * CAP + mt * 64;
    int rend = e * CAP + cnt;
    int n0 = nt * 128;

    __shared__ __attribute__((aligned(16))) bf16_t As[64 * 32];    // 4KB
    __shared__ __attribute__((aligned(16))) bf16_t Bs[128 * 32];   // 8KB

    int tid = threadIdx.x, lane = tid & 63, wid = tid >> 6;
    // A staging: 4 regions x 16 rows, 1 glds16/thread
    int arowL = wid * 16 + (lane >> 2);
    int kk = (lane & 3) * 8;
    int aposc = m0 + arowL; if (aposc > rend - 1) aposc = rend - 1;
    const bf16_t* aP = hws + (size_t)aposc * HDIM + kk;
    int aReg = wid * 512;
    // B staging: 8 regions x 16 rows, 2 glds16/thread
    const bf16_t* bP[2];
    int bReg[2];
    #pragma unroll
    for (int it = 0; it < 2; it++) {
        int region = wid * 2 + it;
        int row = region * 16 + (lane >> 2);
        bP[it] = w2t + ((size_t)e * CDIM + n0 + row) * HDIM + kk;
        bReg[it] = region * 512;
    }

    int wm = (wid & 1) * 32, wn = (wid >> 1) * 64;
    int q = lane >> 4, mr = lane & 15;

    f32x4 acc[2][4];
    #pragma unroll
    for (int i = 0; i < 2; i++)
        #pragma unroll
        for (int j = 0; j < 4; j++)
            acc[i][j] = (f32x4){0.f, 0.f, 0.f, 0.f};

    for (int k0 = 0; k0 < HDIM; k0 += 32) {
        glds16(aP + k0, As + aReg);
        #pragma unroll
        for (int it = 0; it < 2; it++)
            glds16(bP[it] + k0, Bs + bReg[it]);
        __syncthreads();
        bf16x8 af[2], bfr[4];
        #pragma unroll
        for (int ti = 0; ti < 2; ti++)
            af[ti] = *reinterpret_cast<const bf16x8*>(&As[(wm + ti * 16 + mr) * 32 + q * 8]);
        #pragma unroll
        for (int tj = 0; tj < 4; tj++)
            bfr[tj] = *reinterpret_cast<const bf16x8*>(&Bs[(wn + tj * 16 + mr) * 32 + q * 8]);
        #pragma unroll
        for (int ti = 0; ti < 2; ti++)
            #pragma unroll
            for (int tj = 0; tj < 4; tj++)
                acc[ti][tj] = __builtin_amdgcn_mfma_f32_16x16x32_bf16(af[ti], bfr[tj], acc[ti][tj], 0, 0, 0);
        __syncthreads();
    }

    const float* be = b2 + (size_t)e * CDIM + n0;
    #pragma unroll
    for (int ti = 0; ti < 2; ti++) {
        #pragma unroll
        for (int r = 0; r < 4; r++) {
            int pos = m0 + wm + ti * 16 + q * 4 + r;
            if (pos < rend) {
                float g = gmap[pos];
                float* yrow = yws + (size_t)pos * CDIM + n0;
                #pragma unroll
                for (int tj = 0; tj < 4; tj++) {
                    float v = acc[ti][tj][r] + be[wn + tj * 16 + mr];
                    yrow[wn + tj * 16 + mr] = g * v;
                }
            }
        }
    }
}

// ---------- combine: out[t] = yws[slot0(t)] + yws[slot1(t)] ----------
__global__ __launch_bounds__(256)
void combine_kernel(const float* __restrict__ yws, const int* __restrict__ smap,
                    float* __restrict__ out) {
    int idx = blockIdx.x * 256 + threadIdx.x;  // one float4 per thread
    int t = idx / (CDIM / 4);
    int c = (idx - t * (CDIM / 4)) * 4;
    int s0 = smap[t * 2], s1 = smap[t * 2 + 1];
    float4 a = *reinterpret_cast<const float4*>(yws + (size_t)s0 * CDIM + c);
    float4 b = *reinterpret_cast<const float4*>(yws + (size_t)s1 * CDIM + c);
    float4 o = {a.x + b.x, a.y + b.y, a.z + b.z, a.w + b.w};
    *reinterpret_cast<float4*>(out + (size_t)t * CDIM + c) = o;
}

extern "C" void kernel_launch(void* const* d_in, const int* in_sizes, int n_in,
                              void* d_out, int out_size, void* d_ws, size_t ws_size,
                              hipStream_t stream) {
    const float* x  = (const float*)d_in[0];
    const float* wg = (const float*)d_in[1];
    const float* w1 = (const float*)d_in[2];
    const float* b1 = (const float*)d_in[3];
    const float* w2 = (const float*)d_in[4];
    const float* b2 = (const float*)d_in[5];
    float* out = (float*)d_out;

    char* w = (char*)d_ws;
    size_t off = 0;
    bf16_t* xb  = (bf16_t*)(w + off); off += (size_t)NT * CDIM * 2;             // 6.3 MB
    bf16_t* w1t = (bf16_t*)(w + off); off += (size_t)NEXP * CDIM * HDIM * 2;    // 37.7 MB
    bf16_t* w2t = (bf16_t*)(w + off); off += (size_t)NEXP * CDIM * HDIM * 2;    // 37.7 MB
    bf16_t* hws = (bf16_t*)(w + off); off += (size_t)NEXP * CAP * HDIM * 2;     // 62.9 MB
    float* yws  = (float*)w1t;      // 31.5 MB, aliases w1t (dead after GEMM1)
    int* counts = (int*)(w + off);  off += 64;
    int* tmap   = (int*)(w + off);  off += (size_t)NEXP * CAP * 4;
    int* smap   = (int*)(w + off);  off += (size_t)NT * 2 * 4;
    float* gmap = (float*)(w + off);

    hipMemsetAsync(counts, 0, NEXP * sizeof(int), stream);

    transpose_convert_kernel<CDIM, HDIM>
        <<<dim3(HDIM / 64, CDIM / 64, NEXP), 256, 0, stream>>>(w1, w1t);
    transpose_convert_kernel<HDIM, CDIM>
        <<<dim3(CDIM / 64, HDIM / 64, NEXP), 256, 0, stream>>>(w2, w2t);
    router_kernel<<<NT / 32, 512, 0, stream>>>(x, wg, xb, counts, tmap, gmap, smap);

    moe_gemm1_kernel<<<8 * (CAP / 128) * (HDIM / 128), 256, 0, stream>>>(
        xb, w1t, b1, counts, tmap, hws);
    moe_gemm2_kernel<<<8 * (CAP / 64) * (CDIM / 128), 256, 0, stream>>>(
        hws, w2t, b2, counts, gmap, yws);
    combine_kernel<<<NT * (CDIM / 4) / 256, 256, 0, stream>>>(yws, smap, out);
}